// Round 3
// baseline (379.731 us; speedup 1.0000x reference)
//
#include <hip/hip_runtime.h>
#include <hip/hip_bf16.h>

// CIN (xDeepFM) fused 3-layer kernel for MI355X — R15: revert to R12's
// register-W path (best verified, 69.5us) and double TLP: 1024-thr WG =
// 16 waves = 4 waves/SIMD.
// R13/R14 post-mortem: LDS-staged W lost ~10us regardless of sync style
// (drain-0 vs counted vmcnt identical) -> staging itself is the cost: per
// chunk, 32KB DMA-write + 64KB ds_read through LDS ~= the chunk's entire
// MFMA time (reuse/byte too low, unlike big-tile GEMM). Halved L2 traffic
// didn't help => NOT L2-BW-bound. With R10 (not HBM-bound) and R11 (not
// per-wave-ILP-bound), remaining theory: latency-bound at 2 waves/SIMD —
// nothing to run when a wave waits on L2. Fix: 4 waves/SIMD.
// Per-wave state halved to fit the 128-VGPR budget 4/SIMD requires:
//  - L0/L1: wave = (mrow, npair, gs); gs splits the g/kq axis (sfr 32 VGPR,
//    2-field W lookahead 32 VGPR); per-layer partial-sum reduce via 64KB LDS.
//  - step2: 4-way k-split (16 quads/wave); step1: 16 single-tile waves.
// W L2 traffic per CU unchanged (split axis doesn't duplicate); MFMA/SIMD
// unchanged (floor 20.6us). Grid: 256 WGs x 1024 thr. LDS 112KB -> 1 WG/CU.

typedef __attribute__((ext_vector_type(8))) short short8;
typedef __attribute__((ext_vector_type(8))) __bf16 bf16x8;
typedef __attribute__((ext_vector_type(16))) float f32x16;
typedef __attribute__((ext_vector_type(4))) unsigned short u16x4;

#define DEVINL static __device__ __forceinline__

DEVINL unsigned short f2bf_rne(float f) {
  unsigned int u = __builtin_bit_cast(unsigned int, f);
  unsigned int r = u + 0x7fffu + ((u >> 16) & 1u);
  return (unsigned short)(r >> 16);
}

// async global->LDS, 16B per lane; LDS dest = wave-uniform base + lane*16
DEVINL void gload_lds16(const void* g, void* l) {
  __builtin_amdgcn_global_load_lds(
      (const __attribute__((address_space(1))) unsigned int*)g,
      (__attribute__((address_space(3))) unsigned int*)l, 16, 0, 0);
}

// MFMA adapter: builtin may want v8i16 or v8bf16. SFINAE both.
template <typename V>
DEVINL auto mfma_32x32x16_bf16(V a, V b, f32x16 c, int)
    -> decltype(__builtin_amdgcn_mfma_f32_32x32x16_bf16(a, b, c, 0, 0, 0)) {
  return __builtin_amdgcn_mfma_f32_32x32x16_bf16(a, b, c, 0, 0, 0);
}
template <typename V>
DEVINL f32x16 mfma_32x32x16_bf16(V a, V b, f32x16 c, long) {
  return __builtin_amdgcn_mfma_f32_32x32x16_bf16(
      __builtin_bit_cast(bf16x8, a), __builtin_bit_cast(bf16x8, b), c, 0, 0, 0);
}
DEVINL f32x16 mfma_bf16(short8 a, short8 b, f32x16 c) {
  return mfma_32x32x16_bf16(a, b, c, 0);
}

// ---------------- W pack kernel (unchanged, verified R2-R14) ----------------
// Packed layout per layer: [f][kb=k>>3][h][j=k&7] bf16 (granule = 1024 u16).
__global__ void pack_w_kernel(const float* __restrict__ W0,
                              const float* __restrict__ W1,
                              const float* __restrict__ W2,
                              unsigned short* __restrict__ Wt) {
  __shared__ float tile[8][132];
  const int u = blockIdx.x;
  const float* W; int FK, f, kb, base;
  if (u < 128)      { W = W0; FK = 32;  f = u >> 2;         kb = u & 3;          base = 0; }
  else if (u < 640) { W = W1; FK = 128; f = (u - 128) >> 4; kb = (u - 128) & 15; base = 131072; }
  else              { W = W2; FK = 128; f = (u - 640) >> 4; kb = (u - 640) & 15; base = 655360; }
  const int t = threadIdx.x;
#pragma unroll
  for (int i = 0; i < 4; ++i) {
    const int e = t + i * 256;  // 0..1023
    const int kk = e >> 7, h = e & 127;
    tile[kk][h] = W[(f * FK + kb * 8 + kk) * 128 + h];
  }
  __syncthreads();
  unsigned short* dst = Wt + base + f * (FK / 8) * 1024 + kb * 1024;
  const int h = t >> 1;
  const int j0 = (t & 1) * 4;
  u16x4 v;
  v.x = f2bf_rne(tile[j0 + 0][h]);
  v.y = f2bf_rne(tile[j0 + 1][h]);
  v.z = f2bf_rne(tile[j0 + 2][h]);
  v.w = f2bf_rne(tile[j0 + 3][h]);
  *(u16x4*)&dst[t * 4] = v;
}

// -------- layers 0/1: register W path, 16 waves, gs-split over kq ----------
// Frag (field f, global kq) at u16 offset f*FS + kq*2048 + half*1024 + hrow*8
// (FS = 4096 for L0, 16384 for L1). Wave = (mrow, npair, gs): handles kq in
// [gs*KQG, gs*KQG+KQG) for ALL 32 fields; partial Y sums reduced across the
// gs pair through `red` (64KB LDS) before the epilogue (gs==0 waves only).
template <int KQG, int FS, int LAYER>
DEVINL void run_layer(const unsigned short* __restrict__ WtL,
                      const float* __restrict__ bias,
                      const float* x0l,  // LDS-resident x0 block [b][f][d]
                      float* __restrict__ outp, int outoff,
                      unsigned int* SB, float* red,
                      int w, int lane, int mrow, int npair, int gs,
                      int l31, int half) {
  __syncthreads();  // state in SB + x0l ready; red free (prev layer done)

  // B-frags (S) from SB into registers, once per layer.
  // slot (half,j) of sfr[nt][kq] holds S[r][k = (gs*KQG+kq)*16 + half*8 + j],
  // r = npair*64 + nt*32 + l31. SB row k2=k/2 packs (k even lo16, k odd hi16).
  int4 sfr[2][KQG];
  const int rb = npair * 64;
#pragma unroll
  for (int nt = 0; nt < 2; ++nt) {
    const int r = rb + nt * 32 + l31;
#pragma unroll
    for (int kq = 0; kq < KQG; ++kq) {
      const int row0 = (gs * KQG + kq) * 8 + half * 4;
      int4 v;
      v.x = (int)SB[(row0 + 0) * 128 + r];
      v.y = (int)SB[(row0 + 1) * 128 + r];
      v.z = (int)SB[(row0 + 2) * 128 + r];
      v.w = (int)SB[(row0 + 3) * 128 + r];
      sfr[nt][kq] = v;
    }
  }

  f32x16 zv;
#pragma unroll
  for (int e = 0; e < 16; ++e) zv[e] = 0.f;
  f32x16 outacc[2] = {zv, zv};

  const int hrow = mrow * 32 + l31;
  const unsigned short* gb =
      WtL + (size_t)(gs * KQG * 2048 + half * 1024 + hrow * 8);
  const int xb0 = (npair * 2 + 0) * 1024 + l31;  // x0l[b_local][f][d=l31]
  const int xb1 = (npair * 2 + 1) * 1024 + l31;

  auto ldf = [&](short8* wv, int f) {  // this wave's KQG frags of field f
#pragma unroll
    for (int i = 0; i < KQG; ++i)
      wv[i] = *(const short8*)&gb[(size_t)f * FS + i * 2048];
  };
  auto doFld = [&](const short8* wv, float xs0, float xs1) {
    f32x16 Y0, Y1;
#pragma unroll
    for (int i = 0; i < KQG; ++i) {
      const short8 s0 = __builtin_bit_cast(short8, sfr[0][i]);
      const short8 s1 = __builtin_bit_cast(short8, sfr[1][i]);
      Y0 = mfma_bf16(wv[i], s0, i == 0 ? zv : Y0);
      Y1 = mfma_bf16(wv[i], s1, i == 0 ? zv : Y1);
    }
#pragma unroll
    for (int e = 0; e < 16; ++e) {
      outacc[0][e] += xs0 * Y0[e];
      outacc[1][e] += xs1 * Y1[e];
    }
  };

  short8 wa[KQG], wb[KQG];
  ldf(wa, 0);
  ldf(wb, 1);
#pragma unroll 1
  for (int f2 = 0; f2 < 16; ++f2) {
    const int f = 2 * f2;
    const float xs00 = x0l[xb0 + f * 32], xs01 = x0l[xb1 + f * 32];
    const float xs10 = x0l[xb0 + (f + 1) * 32], xs11 = x0l[xb1 + (f + 1) * 32];
    doFld(wa, xs00, xs01);
    if (f2 < 15) ldf(wa, f + 2);
    doFld(wb, xs10, xs11);
    if (f2 < 15) ldf(wb, f + 3);
  }

  // --- gs partial-sum reduction (red: [widx][nt][e][lane] f32, 64KB) ---
  const int widx = w & 7;  // (npair<<2)|mrow — shared by the gs pair
  if (gs) {
#pragma unroll
    for (int nt = 0; nt < 2; ++nt)
#pragma unroll
      for (int e = 0; e < 16; ++e)
        red[((widx * 2 + nt) * 16 + e) * 64 + lane] = outacc[nt][e];
  }
  __syncthreads();  // also: all sfr reads done -> SB writable below
  if (gs) return;   // gs==1 waves rejoin at the next layer's entry barrier
#pragma unroll
  for (int nt = 0; nt < 2; ++nt)
#pragma unroll
    for (int e = 0; e < 16; ++e)
      outacc[nt][e] += red[((widx * 2 + nt) * 16 + e) * 64 + lane];

  // --- epilogue (gs==0 waves; unchanged R9 math) ---
  // C/D layout: col = lane&31 = n; row = (reg&3)+8*(reg>>2)+4*half = h.
  float bv[16];
#pragma unroll
  for (int e = 0; e < 16; ++e)
    bv[e] = bias[mrow * 32 + (e & 3) + 8 * (e >> 2) + 4 * half];

  if constexpr (LAYER < 2) {
    // next state S'[r][h] = bf16(acc+bias), packed [h/2][r] u32 into SB
#pragma unroll
    for (int nt = 0; nt < 2; ++nt) {
      const int r = rb + nt * 32 + l31;
#pragma unroll
      for (int g = 0; g < 4; ++g) {
        const int h2 = mrow * 16 + 4 * g + 2 * half;
        const float v0 = outacc[nt][4 * g + 0] + bv[4 * g + 0];
        const float v1 = outacc[nt][4 * g + 1] + bv[4 * g + 1];
        const float v2 = outacc[nt][4 * g + 2] + bv[4 * g + 2];
        const float v3 = outacc[nt][4 * g + 3] + bv[4 * g + 3];
        SB[h2 * 128 + r] =
            (unsigned)f2bf_rne(v0) | ((unsigned)f2bf_rne(v1) << 16);
        SB[(h2 + 1) * 128 + r] =
            (unsigned)f2bf_rne(v2) | ((unsigned)f2bf_rne(v3) << 16);
      }
    }
  }

  // final output: out[b, outoff+h] = sum_d acc + 32*bias (d = l31 lanes)
#pragma unroll
  for (int nt = 0; nt < 2; ++nt) {
    float sv[16];
#pragma unroll
    for (int e = 0; e < 16; ++e) {
      float v = outacc[nt][e];
      v += __shfl_xor(v, 1);
      v += __shfl_xor(v, 2);
      v += __shfl_xor(v, 4);
      v += __shfl_xor(v, 8);
      v += __shfl_xor(v, 16);
      sv[e] = v + 32.0f * bv[e];
    }
    if (l31 == 0) {
      const int b = npair * 2 + nt;
#pragma unroll
      for (int g = 0; g < 4; ++g) {
        const int h = mrow * 32 + 8 * g + 4 * half;
        float4 o = {sv[4 * g + 0], sv[4 * g + 1], sv[4 * g + 2], sv[4 * g + 3]};
        *(float4*)&outp[b * 384 + outoff + h] = o;
      }
    }
  }
}

// ---------------- layer 2, U-trick (R12 structure, 16 waves) ----------------
// out2[b,h] = sum_k U[b,k]*W2[k,h] + 32*b2[h];  U[b,f*128+g] = x0_b . S2_b^T.
DEVINL void run_layer2_fast(const unsigned short* __restrict__ WtL,
                            const float* __restrict__ bias,
                            const float* x0l,
                            float* __restrict__ outp,
                            unsigned int* SB,
                            int w, int l31, int half, int tid) {
  __syncthreads();  // S2 in SB ready ([g/2][r=b*32+d] u32 bf16-pairs)

  f32x16 zv;
#pragma unroll
  for (int e = 0; e < 16; ++e) zv[e] = 0.f;

  // ---- step 1: U = x0_b (32f x 32d) . S2_b^T (32d x 128g), MFMA M=f,N=g,K=d
  // 16 waves: batch bw = w>>2 (0..3), g-tile gq = w&3 (0..3).
  const int bw = w >> 2, gq = w & 3;
  short8 a1[2];  // A[m=f=l31][k=d slots], kq=0,1  (reads from LDS x0l)
  {
    const float* xr = &x0l[bw * 1024 + l31 * 32];
#pragma unroll
    for (int kq = 0; kq < 2; ++kq) {
      const int d0 = kq * 16 + half * 8;
      union { short8 v; unsigned short u[8]; } t;
#pragma unroll
      for (int j = 0; j < 8; ++j) t.u[j] = f2bf_rne(xr[d0 + j]);
      a1[kq] = t.v;
    }
  }
  short8 bfr[2];  // [kq]: B[k=d][n=g]: S2[b, g, d],  g = gq*32 + l31
  {
    const int g = gq * 32 + l31;
    const unsigned int* row = &SB[(g >> 1) * 128 + bw * 32];
    const int sh = (g & 1) * 16;
#pragma unroll
    for (int kq = 0; kq < 2; ++kq) {
      const int d0 = kq * 16 + half * 8;
      union { short8 v; unsigned short u[8]; } t;
#pragma unroll
      for (int j = 0; j < 8; ++j)
        t.u[j] = (unsigned short)(row[d0 + j] >> sh);
      bfr[kq] = t.v;
    }
  }
  f32x16 ua = mfma_bf16(a1[0], bfr[0], zv);
  ua = mfma_bf16(a1[1], bfr[1], ua);
  __syncthreads();  // all waves done reading S2 from SB

  // ---- write U into SB as U32[k2 = k/2][b] (k = f*128+g; u16 writes) ----
  unsigned short* U16 = (unsigned short*)SB;
  {
    const int g = gq * 32 + l31;
#pragma unroll
    for (int reg = 0; reg < 16; ++reg) {
      const int f = (reg & 3) + 8 * (reg >> 2) + 4 * half;
      const int k = f * 128 + g;
      U16[(k >> 1) * 8 + bw * 2 + (k & 1)] = f2bf_rne(ua[reg]);
    }
  }
  __syncthreads();  // U ready

  // ---- step 2: D[m=h][n=b] = sum_k W2[k,h]*U[b,k]; mt = w&3, kh = w>>2 ----
  const int mt = w & 3, kh = w >> 2;  // kh 0..3: 4-way k-split, 16 quads each
  const char* gb = (const char*)WtL +
                   (size_t)(half * 2048 + (mt * 32 + l31) * 16);
  const int bl = l31 & 3;  // lanes 4..31 duplicate b (cols unused, bounds-safe)

  auto ldq2 = [&](short8* wv, int q) {  // quad q -> kq = 4q..4q+3
#pragma unroll
    for (int i = 0; i < 4; ++i)
      wv[i] = *(const short8*)(gb + (size_t)q * 16384 + i * 4096);
  };
  auto breadq = [&](short8* bv, int q) {  // B-frags for the 4 kq of quad q
#pragma unroll
    for (int i = 0; i < 4; ++i) {
      const int row0 = (q * 4 + i) * 8 + half * 4;
      int4 v;
      v.x = (int)SB[(row0 + 0) * 4 + bl];
      v.y = (int)SB[(row0 + 1) * 4 + bl];
      v.z = (int)SB[(row0 + 2) * 4 + bl];
      v.w = (int)SB[(row0 + 3) * 4 + bl];
      bv[i] = __builtin_bit_cast(short8, v);
    }
  };

  f32x16 acc0 = zv, acc1 = zv;
  short8 qa[4], qb[4], Ba[4], Bb[4];
  const int q0 = kh * 16;  // 16 quads = 64 kq per wave
  ldq2(qa, q0);
  breadq(Ba, q0);
#pragma unroll 1
  for (int qq = 0; qq < 8; ++qq) {
    const int q = q0 + 2 * qq;
    ldq2(qb, q + 1);
    breadq(Bb, q + 1);
#pragma unroll
    for (int i = 0; i < 4; ++i) acc0 = mfma_bf16(qa[i], Ba[i], acc0);
    if (qq < 7) {
      ldq2(qa, q + 2);
      breadq(Ba, q + 2);
    }
#pragma unroll
    for (int i = 0; i < 4; ++i) acc1 = mfma_bf16(qb[i], Bb[i], acc1);
  }
#pragma unroll
  for (int e = 0; e < 16; ++e) acc0[e] += acc1[e];

  __syncthreads();  // all waves done reading U from SB

  // ---- partials P[o = b*128 + h][kh 0..3] f32 into SB (8KB), reduce ----
  float* P = (float*)SB;
  if (l31 < 4) {
#pragma unroll
    for (int reg = 0; reg < 16; ++reg) {
      const int h = mt * 32 + (reg & 3) + 8 * (reg >> 2) + 4 * half;
      P[(l31 * 128 + h) * 4 + kh] = acc0[reg];
    }
  }
  __syncthreads();
  if (tid < 512) {
    const int b = tid >> 7, h = tid & 127;  // 512 outputs
    const float v = P[tid * 4 + 0] + P[tid * 4 + 1] + P[tid * 4 + 2] +
                    P[tid * 4 + 3] + 32.0f * bias[h];
    outp[b * 384 + 256 + h] = v;
  }
}

__global__ __launch_bounds__(1024, 4) void cin_kernel(
    const float* __restrict__ x0g, const unsigned short* __restrict__ Wt,
    const float* __restrict__ b0, const float* __restrict__ b1,
    const float* __restrict__ b2, float* __restrict__ out) {
  __shared__ unsigned int SB[64 * 128];       // 32KB state / U / partials
  __shared__ __align__(16) float x0l[4096];   // 16KB x0 block [b][f][d]
  __shared__ __align__(16) float red[16384];  // 64KB gs-reduction scratch

  const int t = threadIdx.x;
  const int lane = t & 63;
  const int w = t >> 6;             // 0..15
  const int mrow = w & 3;           // h-tile of 32 (L0/L1)
  const int npair = (w >> 2) & 1;   // batch pair (L0/L1)
  const int gs = w >> 3;            // kq-half split (L0/L1)
  const int l31 = lane & 31, half = lane >> 5;
  const int wgb0 = blockIdx.x * 4;  // 4 batches per WG

  // prologue A: stage x0 block -> LDS via global_load_lds (16 x 1KB)
  const float* xsrc = x0g + (size_t)wgb0 * 1024;
  gload_lds16(xsrc + w * 256 + lane * 4, x0l + w * 256);
  // prologue B: S1 = bf16(x0^T) -> SB ([g/2][r] u32, r = b_local*32+d)
#pragma unroll
  for (int s = 0; s < 2; ++s) {
    const int i = t + s * 1024;  // 0..2047
    const int r = i & 127, g2 = i >> 7;
    const float* p = &x0g[(wgb0 + (r >> 5)) * 1024 + (2 * g2) * 32 + (r & 31)];
    SB[g2 * 128 + r] =
        (unsigned)f2bf_rne(p[0]) | ((unsigned)f2bf_rne(p[32]) << 16);
  }
  // visibility handled by the entry barrier in run_layer (full drain)

  float* outp = out + (size_t)wgb0 * 384;
  run_layer<1, 4096, 0>(Wt, b0, x0l, outp, 0, SB, red, w, lane, mrow, npair,
                        gs, l31, half);
  run_layer<4, 16384, 1>(Wt + 131072, b1, x0l, outp, 128, SB, red, w, lane,
                         mrow, npair, gs, l31, half);
  run_layer2_fast(Wt + 655360, b2, x0l, outp, SB, w, l31, half, t);
}

extern "C" void kernel_launch(void* const* d_in, const int* in_sizes, int n_in,
                              void* d_out, int out_size, void* d_ws, size_t ws_size,
                              hipStream_t stream) {
  (void)in_sizes; (void)n_in; (void)out_size; (void)ws_size;
  const float* x0 = (const float*)d_in[0];
  const float* W0 = (const float*)d_in[1];
  const float* W1 = (const float*)d_in[2];
  const float* W2 = (const float*)d_in[3];
  const float* b0 = (const float*)d_in[4];
  const float* b1 = (const float*)d_in[5];
  const float* b2 = (const float*)d_in[6];
  unsigned short* Wt = (unsigned short*)d_ws;  // 2,359,296 B

  pack_w_kernel<<<1152, 256, 0, stream>>>(W0, W1, W2, Wt);
  // 256 WGs x 1024 thr = 1 WG/CU (16 waves, 4/SIMD)
  cin_kernel<<<256, 1024, 0, stream>>>(x0, Wt, b0, b1, b2, (float*)d_out);
}

// Round 5
// 198.913 us; speedup vs baseline: 1.9090x; 1.9090x over previous
//
#include <hip/hip_runtime.h>
#include <hip/hip_bf16.h>

// CIN (xDeepFM) fused 3-layer kernel for MI355X — R17: identical resubmit of
// R16 (bench died with a Trio-nursery infra exception, no verdict/profile).
// Kernel audited: no barrier divergence (gs-return after the reduce barrier,
// epilogue barrier-free), W reads exactly in-bounds at region edges, LDS
// 112KB, ~200 live VGPR < 256 cap -> no forced spill. Hypothesis unchanged:
// R12's npair waves load IDENTICAL W frags (2x L2 duplication, 2 MFMA per
// 16B frag). This re-split (wave = mrow x gs; gs halves kq; each wave does
// all 4 batches) halves W L2 traffic/CU in-register (no LDS round-trip,
// which R13/R14 showed eats the gain), 4 MFMA per frag, 4 loads/field/wave.
// Cost: per-layer gs partial-sum reduce via 64KB LDS (~0.4us; split+reduce
// math correctness-verified by R15's passing run).
// Step1/step2/prologue/pack verbatim R12. Grid: 256 WGs x 512 thr. LDS 112KB.

typedef __attribute__((ext_vector_type(8))) short short8;
typedef __attribute__((ext_vector_type(8))) __bf16 bf16x8;
typedef __attribute__((ext_vector_type(16))) float f32x16;
typedef __attribute__((ext_vector_type(4))) unsigned short u16x4;

#define DEVINL static __device__ __forceinline__

DEVINL unsigned short f2bf_rne(float f) {
  unsigned int u = __builtin_bit_cast(unsigned int, f);
  unsigned int r = u + 0x7fffu + ((u >> 16) & 1u);
  return (unsigned short)(r >> 16);
}

// async global->LDS, 16B per lane; LDS dest = wave-uniform base + lane*16
DEVINL void gload_lds16(const void* g, void* l) {
  __builtin_amdgcn_global_load_lds(
      (const __attribute__((address_space(1))) unsigned int*)g,
      (__attribute__((address_space(3))) unsigned int*)l, 16, 0, 0);
}

// MFMA adapter: builtin may want v8i16 or v8bf16. SFINAE both.
template <typename V>
DEVINL auto mfma_32x32x16_bf16(V a, V b, f32x16 c, int)
    -> decltype(__builtin_amdgcn_mfma_f32_32x32x16_bf16(a, b, c, 0, 0, 0)) {
  return __builtin_amdgcn_mfma_f32_32x32x16_bf16(a, b, c, 0, 0, 0);
}
template <typename V>
DEVINL f32x16 mfma_32x32x16_bf16(V a, V b, f32x16 c, long) {
  return __builtin_amdgcn_mfma_f32_32x32x16_bf16(
      __builtin_bit_cast(bf16x8, a), __builtin_bit_cast(bf16x8, b), c, 0, 0, 0);
}
DEVINL f32x16 mfma_bf16(short8 a, short8 b, f32x16 c) {
  return mfma_32x32x16_bf16(a, b, c, 0);
}

// ---------------- W pack kernel (unchanged, verified R2-R15) ----------------
// Packed layout per layer: [f][kb=k>>3][h][j=k&7] bf16 (granule = 1024 u16).
__global__ void pack_w_kernel(const float* __restrict__ W0,
                              const float* __restrict__ W1,
                              const float* __restrict__ W2,
                              unsigned short* __restrict__ Wt) {
  __shared__ float tile[8][132];
  const int u = blockIdx.x;
  const float* W; int FK, f, kb, base;
  if (u < 128)      { W = W0; FK = 32;  f = u >> 2;         kb = u & 3;          base = 0; }
  else if (u < 640) { W = W1; FK = 128; f = (u - 128) >> 4; kb = (u - 128) & 15; base = 131072; }
  else              { W = W2; FK = 128; f = (u - 640) >> 4; kb = (u - 640) & 15; base = 655360; }
  const int t = threadIdx.x;
#pragma unroll
  for (int i = 0; i < 4; ++i) {
    const int e = t + i * 256;  // 0..1023
    const int kk = e >> 7, h = e & 127;
    tile[kk][h] = W[(f * FK + kb * 8 + kk) * 128 + h];
  }
  __syncthreads();
  unsigned short* dst = Wt + base + f * (FK / 8) * 1024 + kb * 1024;
  const int h = t >> 1;
  const int j0 = (t & 1) * 4;
  u16x4 v;
  v.x = f2bf_rne(tile[j0 + 0][h]);
  v.y = f2bf_rne(tile[j0 + 1][h]);
  v.z = f2bf_rne(tile[j0 + 2][h]);
  v.w = f2bf_rne(tile[j0 + 3][h]);
  *(u16x4*)&dst[t * 4] = v;
}

// ------- layers 0/1: register W, wave = (mrow, gs), 4 n-tiles/wave ---------
// Frag (field f, global kq) at u16 offset f*FS + kq*2048 + half*1024 + hrow*8.
// Wave (mrow, gs): m-tile mrow, kq in [gs*KQG, gs*KQG+KQG), ALL 4 n-tiles
// (nt = batch). Partial Y sums over the gs pair reduced via `red` (64KB LDS);
// epilogue on gs==0 waves only.
template <int KQG, int FS, int LAYER>
DEVINL void run_layer(const unsigned short* __restrict__ WtL,
                      const float* __restrict__ bias,
                      const float* x0l,  // LDS-resident x0 block [b][f][d]
                      float* __restrict__ outp, int outoff,
                      unsigned int* SB, float* red,
                      int lane, int mrow, int gs, int l31, int half) {
  __syncthreads();  // state in SB + x0l ready (prologue or previous epilogue)

  // B-frags (S) from SB into registers, once per layer.
  // slot (half,j) of sfr[nt][kq] holds S[r][k = (gs*KQG+kq)*16 + half*8 + j],
  // r = nt*32 + l31. SB row k2=k/2 packs (k even lo16, k odd hi16).
  int4 sfr[4][KQG];
#pragma unroll
  for (int nt = 0; nt < 4; ++nt) {
    const int r = nt * 32 + l31;
#pragma unroll
    for (int kq = 0; kq < KQG; ++kq) {
      const int row0 = (gs * KQG + kq) * 8 + half * 4;
      int4 v;
      v.x = (int)SB[(row0 + 0) * 128 + r];
      v.y = (int)SB[(row0 + 1) * 128 + r];
      v.z = (int)SB[(row0 + 2) * 128 + r];
      v.w = (int)SB[(row0 + 3) * 128 + r];
      sfr[nt][kq] = v;
    }
  }

  f32x16 zv;
#pragma unroll
  for (int e = 0; e < 16; ++e) zv[e] = 0.f;
  f32x16 outacc[4] = {zv, zv, zv, zv};

  const int hrow = mrow * 32 + l31;
  const unsigned short* gb =
      WtL + (size_t)(gs * KQG * 2048 + half * 1024 + hrow * 8);

  auto ldf = [&](short8* wv, int f) {  // this wave's KQG frags of field f
#pragma unroll
    for (int i = 0; i < KQG; ++i)
      wv[i] = *(const short8*)&gb[(size_t)f * FS + i * 2048];
  };
  auto doFld = [&](const short8* wv, int f) {
#pragma unroll
    for (int np = 0; np < 2; ++np) {  // n-tile pairs: keeps only 2 Y live
      const float xsA = x0l[(2 * np + 0) * 1024 + f * 32 + l31];
      const float xsB = x0l[(2 * np + 1) * 1024 + f * 32 + l31];
      f32x16 Y0, Y1;
#pragma unroll
      for (int i = 0; i < KQG; ++i) {
        const short8 sA = __builtin_bit_cast(short8, sfr[2 * np + 0][i]);
        const short8 sB = __builtin_bit_cast(short8, sfr[2 * np + 1][i]);
        Y0 = mfma_bf16(wv[i], sA, i == 0 ? zv : Y0);
        Y1 = mfma_bf16(wv[i], sB, i == 0 ? zv : Y1);
      }
#pragma unroll
      for (int e = 0; e < 16; ++e) {
        outacc[2 * np + 0][e] += xsA * Y0[e];
        outacc[2 * np + 1][e] += xsB * Y1[e];
      }
    }
  };

  short8 wa[KQG], wb[KQG];
  ldf(wa, 0);
  ldf(wb, 1);
#pragma unroll 1
  for (int f2 = 0; f2 < 16; ++f2) {
    const int f = 2 * f2;
    doFld(wa, f);
    if (f2 < 15) ldf(wa, f + 2);
    doFld(wb, f + 1);
    if (f2 < 15) ldf(wb, f + 3);
  }

  // --- gs partial-sum reduction (red: [mrow][nt][e][lane] f32, 64KB) ---
  if (gs) {
#pragma unroll
    for (int nt = 0; nt < 4; ++nt)
#pragma unroll
      for (int e = 0; e < 16; ++e)
        red[((mrow * 4 + nt) * 16 + e) * 64 + lane] = outacc[nt][e];
  }
  __syncthreads();  // partials visible; all sfr reads done -> SB writable
  if (gs) return;   // gs==1 waves rejoin at the next phase's entry barrier
#pragma unroll
  for (int nt = 0; nt < 4; ++nt)
#pragma unroll
    for (int e = 0; e < 16; ++e)
      outacc[nt][e] += red[((mrow * 4 + nt) * 16 + e) * 64 + lane];

  // --- epilogue (gs==0 waves; R12 math, nt = batch 0..3) ---
  // C/D layout: col = lane&31 = n; row = (reg&3)+8*(reg>>2)+4*half = h.
  float bv[16];
#pragma unroll
  for (int e = 0; e < 16; ++e)
    bv[e] = bias[mrow * 32 + (e & 3) + 8 * (e >> 2) + 4 * half];

  if constexpr (LAYER < 2) {
    // next state S'[r][h] = bf16(acc+bias), packed [h/2][r] u32 into SB
#pragma unroll
    for (int nt = 0; nt < 4; ++nt) {
      const int r = nt * 32 + l31;
#pragma unroll
      for (int g = 0; g < 4; ++g) {
        const int h2 = mrow * 16 + 4 * g + 2 * half;
        const float v0 = outacc[nt][4 * g + 0] + bv[4 * g + 0];
        const float v1 = outacc[nt][4 * g + 1] + bv[4 * g + 1];
        const float v2 = outacc[nt][4 * g + 2] + bv[4 * g + 2];
        const float v3 = outacc[nt][4 * g + 3] + bv[4 * g + 3];
        SB[h2 * 128 + r] =
            (unsigned)f2bf_rne(v0) | ((unsigned)f2bf_rne(v1) << 16);
        SB[(h2 + 1) * 128 + r] =
            (unsigned)f2bf_rne(v2) | ((unsigned)f2bf_rne(v3) << 16);
      }
    }
  }

  // final output: out[b, outoff+h] = sum_d acc + 32*bias (d = l31 lanes)
#pragma unroll
  for (int nt = 0; nt < 4; ++nt) {
    float sv[16];
#pragma unroll
    for (int e = 0; e < 16; ++e) {
      float v = outacc[nt][e];
      v += __shfl_xor(v, 1);
      v += __shfl_xor(v, 2);
      v += __shfl_xor(v, 4);
      v += __shfl_xor(v, 8);
      v += __shfl_xor(v, 16);
      sv[e] = v + 32.0f * bv[e];
    }
    if (l31 == 0) {
      const int b = nt;
#pragma unroll
      for (int g = 0; g < 4; ++g) {
        const int h = mrow * 32 + 8 * g + 4 * half;
        float4 o = {sv[4 * g + 0], sv[4 * g + 1], sv[4 * g + 2], sv[4 * g + 3]};
        *(float4*)&outp[b * 384 + outoff + h] = o;
      }
    }
  }
}

// ---------------- layer 2, U-trick (verbatim R12; register W path) ---------
// out2[b,h] = sum_k U[b,k]*W2[k,h] + 32*b2[h];  U[b,f*128+g] = x0_b . S2_b^T.
DEVINL void run_layer2_fast(const unsigned short* __restrict__ WtL,
                            const float* __restrict__ bias,
                            const float* x0l,
                            float* __restrict__ outp,
                            unsigned int* SB,
                            int w, int l31, int half, int tid) {
  __syncthreads();  // S2 in SB ready ([g/2][r=b*32+d] u32 bf16-pairs)

  f32x16 zv;
#pragma unroll
  for (int e = 0; e < 16; ++e) zv[e] = 0.f;

  // ---- step 1: U = x0_b (32f x 32d) . S2_b^T (32d x 128g), MFMA M=f,N=g,K=d
  // wave w: batch bw = w>>1, g-half gh = w&1 (2 n-tiles of g).
  const int bw = w >> 1, gh = w & 1;
  short8 a1[2];  // A[m=f=l31][k=d slots], kq=0,1  (reads from LDS x0l)
  {
    const float* xr = &x0l[bw * 1024 + l31 * 32];
#pragma unroll
    for (int kq = 0; kq < 2; ++kq) {
      const int d0 = kq * 16 + half * 8;
      union { short8 v; unsigned short u[8]; } t;
#pragma unroll
      for (int j = 0; j < 8; ++j) t.u[j] = f2bf_rne(xr[d0 + j]);
      a1[kq] = t.v;
    }
  }
  short8 bfr[2][2];  // [nt][kq]: B[k=d][n=g]: S2[b, g, d]
#pragma unroll
  for (int nt = 0; nt < 2; ++nt) {
    const int g = gh * 64 + nt * 32 + l31;
    const unsigned int* row = &SB[(g >> 1) * 128 + bw * 32];
    const int sh = (g & 1) * 16;
#pragma unroll
    for (int kq = 0; kq < 2; ++kq) {
      const int d0 = kq * 16 + half * 8;
      union { short8 v; unsigned short u[8]; } t;
#pragma unroll
      for (int j = 0; j < 8; ++j)
        t.u[j] = (unsigned short)(row[d0 + j] >> sh);
      bfr[nt][kq] = t.v;
    }
  }
  f32x16 ua[2];
#pragma unroll
  for (int nt = 0; nt < 2; ++nt) {
    ua[nt] = mfma_bf16(a1[0], bfr[nt][0], zv);
    ua[nt] = mfma_bf16(a1[1], bfr[nt][1], ua[nt]);
  }
  __syncthreads();  // all waves done reading S2 from SB

  // ---- write U into SB as U32[k2 = k/2][b] (k = f*128+g; u16 writes) ----
  unsigned short* U16 = (unsigned short*)SB;
#pragma unroll
  for (int nt = 0; nt < 2; ++nt) {
    const int g = gh * 64 + nt * 32 + l31;
#pragma unroll
    for (int reg = 0; reg < 16; ++reg) {
      const int f = (reg & 3) + 8 * (reg >> 2) + 4 * half;
      const int k = f * 128 + g;
      U16[(k >> 1) * 8 + bw * 2 + (k & 1)] = f2bf_rne(ua[nt][reg]);
    }
  }
  __syncthreads();  // U ready

  // ---- step 2: D[m=h][n=b] = sum_k W2[k,h]*U[b,k]; wave: mt=w&3, kh=w>>2 ----
  const int mt = w & 3, kh = w >> 2;
  const char* gb = (const char*)WtL +
                   (size_t)(half * 2048 + (mt * 32 + l31) * 16);
  const int bl = l31 & 3;  // lanes 4..31 duplicate b (cols unused, bounds-safe)

  auto ldq2 = [&](short8* wv, int q) {  // quad q -> kq = 4q..4q+3
#pragma unroll
    for (int i = 0; i < 4; ++i)
      wv[i] = *(const short8*)(gb + (size_t)q * 16384 + i * 4096);
  };
  auto breadq = [&](short8* bv, int q) {  // B-frags for the 4 kq of quad q
#pragma unroll
    for (int i = 0; i < 4; ++i) {
      const int row0 = (q * 4 + i) * 8 + half * 4;
      int4 v;
      v.x = (int)SB[(row0 + 0) * 4 + bl];
      v.y = (int)SB[(row0 + 1) * 4 + bl];
      v.z = (int)SB[(row0 + 2) * 4 + bl];
      v.w = (int)SB[(row0 + 3) * 4 + bl];
      bv[i] = __builtin_bit_cast(short8, v);
    }
  };

  f32x16 acc0 = zv, acc1 = zv;
  short8 qa[4], qb[4], Ba[4], Bb[4];
  const int q0 = kh * 32;  // 32 quads = 128 kq per wave
  ldq2(qa, q0);
  breadq(Ba, q0);
#pragma unroll 1
  for (int qq = 0; qq < 16; ++qq) {
    const int q = q0 + 2 * qq;
    ldq2(qb, q + 1);
    breadq(Bb, q + 1);
#pragma unroll
    for (int i = 0; i < 4; ++i) acc0 = mfma_bf16(qa[i], Ba[i], acc0);
    if (qq < 15) {
      ldq2(qa, q + 2);
      breadq(Ba, q + 2);
    }
#pragma unroll
    for (int i = 0; i < 4; ++i) acc1 = mfma_bf16(qb[i], Bb[i], acc1);
  }
#pragma unroll
  for (int e = 0; e < 16; ++e) acc0[e] += acc1[e];

  __syncthreads();  // all waves done reading U from SB

  // ---- partials P[o = b*128 + h][kh] f32 into SB (4KB), then reduce ----
  float* P = (float*)SB;
  if (l31 < 4) {
#pragma unroll
    for (int reg = 0; reg < 16; ++reg) {
      const int h = mt * 32 + (reg & 3) + 8 * (reg >> 2) + 4 * half;
      P[(l31 * 128 + h) * 2 + kh] = acc0[reg];
    }
  }
  __syncthreads();
  {
    const int b = tid >> 7, h = tid & 127;  // tid 0..511 -> all outputs
    const float v = P[tid * 2] + P[tid * 2 + 1] + 32.0f * bias[h];
    outp[b * 384 + 256 + h] = v;
  }
}

__global__ __launch_bounds__(512, 2) void cin_kernel(
    const float* __restrict__ x0g, const unsigned short* __restrict__ Wt,
    const float* __restrict__ b0, const float* __restrict__ b1,
    const float* __restrict__ b2, float* __restrict__ out) {
  __shared__ unsigned int SB[64 * 128];       // 32KB state / U / partials
  __shared__ __align__(16) float x0l[4096];   // 16KB x0 block [b][f][d]
  __shared__ __align__(16) float red[16384];  // 64KB gs-reduction scratch

  const int t = threadIdx.x;
  const int lane = t & 63;
  const int w = t >> 6;    // 0..7
  const int mrow = w & 3;  // h-tile of 32 (L0/L1)
  const int gs = w >> 2;   // kq-half split (L0/L1)
  const int l31 = lane & 31, half = lane >> 5;
  const int wgb0 = blockIdx.x * 4;  // 4 batches per WG

  // prologue A: stage x0 block -> LDS via global_load_lds (16 chunks x 1KB)
  const float* xsrc = x0g + (size_t)wgb0 * 1024;
#pragma unroll
  for (int c = 0; c < 2; ++c) {
    const int chunk = w * 2 + c;
    gload_lds16(xsrc + chunk * 256 + lane * 4, x0l + chunk * 256);
  }
  // prologue B: S1 = bf16(x0^T) -> SB ([g/2][r] u32, r = b_local*32+d)
#pragma unroll
  for (int s = 0; s < 4; ++s) {
    const int i = t + s * 512;  // 0..2047
    const int r = i & 127, g2 = i >> 7;
    const float* p = &x0g[(wgb0 + (r >> 5)) * 1024 + (2 * g2) * 32 + (r & 31)];
    SB[g2 * 128 + r] =
        (unsigned)f2bf_rne(p[0]) | ((unsigned)f2bf_rne(p[32]) << 16);
  }
  // visibility handled by the entry barrier in run_layer (full drain)

  float* outp = out + (size_t)wgb0 * 384;
  run_layer<1, 4096, 0>(Wt, b0, x0l, outp, 0, SB, red, lane, mrow, gs, l31,
                        half);
  run_layer<4, 16384, 1>(Wt + 131072, b1, x0l, outp, 128, SB, red, lane, mrow,
                         gs, l31, half);
  run_layer2_fast(Wt + 655360, b2, x0l, outp, SB, w, l31, half, t);
}

extern "C" void kernel_launch(void* const* d_in, const int* in_sizes, int n_in,
                              void* d_out, int out_size, void* d_ws, size_t ws_size,
                              hipStream_t stream) {
  (void)in_sizes; (void)n_in; (void)out_size; (void)ws_size;
  const float* x0 = (const float*)d_in[0];
  const float* W0 = (const float*)d_in[1];
  const float* W1 = (const float*)d_in[2];
  const float* W2 = (const float*)d_in[3];
  const float* b0 = (const float*)d_in[4];
  const float* b1 = (const float*)d_in[5];
  const float* b2 = (const float*)d_in[6];
  unsigned short* Wt = (unsigned short*)d_ws;  // 2,359,296 B

  pack_w_kernel<<<1152, 256, 0, stream>>>(W0, W1, W2, Wt);
  // 256 WGs x 512 thr = 1 WG/CU (8 waves, 2/SIMD)
  cin_kernel<<<256, 512, 0, stream>>>(x0, Wt, b0, b1, b2, (float*)d_out);
}

// Round 7
// 132.604 us; speedup vs baseline: 2.8636x; 1.5001x over previous
//
#include <hip/hip_runtime.h>
#include <hip/hip_bf16.h>

// CIN (xDeepFM) fused 3-layer kernel for MI355X — R19: identical resubmit of
// R18 (bench died with "MI355X container failed twice" — infra, no verdict).
// Kernel audited: unconditional barriers only, constant trip counts, all
// reload-clamp addresses end exactly at region bounds (in-bounds), LDS 48KB,
// step2 live set ~190 VGPR < 256 cap. Hypothesis unchanged from R18:
// R12 is latency-stall-bound (MFMA floor ~5us, L2 stream ~26us serial,
// measured 69.5us, both utils ~30%); its W prefetch distance is ~1 phase
// (L1 ~256cyc, L0 ~128, step2 ~64-128) vs 200-500cyc L2 latency under load
// at 2 waves/SIMD. Fix: reload each W buffer register right after its last
// MFMA use targeting +2 phases ahead (distance doubles, zero extra VGPR in
// L0/L1); step2 deepens to 4 quad+B buffers (+64 VGPR where L1 state is
// dead). Math/layout/barriers verbatim R12. Grid: 256 WGs x 512 thr.

typedef __attribute__((ext_vector_type(8))) short short8;
typedef __attribute__((ext_vector_type(8))) __bf16 bf16x8;
typedef __attribute__((ext_vector_type(16))) float f32x16;
typedef __attribute__((ext_vector_type(4))) unsigned short u16x4;

#define DEVINL static __device__ __forceinline__

DEVINL unsigned short f2bf_rne(float f) {
  unsigned int u = __builtin_bit_cast(unsigned int, f);
  unsigned int r = u + 0x7fffu + ((u >> 16) & 1u);
  return (unsigned short)(r >> 16);
}

// async global->LDS, 16B per lane; LDS dest = wave-uniform base + lane*16
DEVINL void gload_lds16(const void* g, void* l) {
  __builtin_amdgcn_global_load_lds(
      (const __attribute__((address_space(1))) unsigned int*)g,
      (__attribute__((address_space(3))) unsigned int*)l, 16, 0, 0);
}

// MFMA adapter: builtin may want v8i16 or v8bf16. SFINAE both.
template <typename V>
DEVINL auto mfma_32x32x16_bf16(V a, V b, f32x16 c, int)
    -> decltype(__builtin_amdgcn_mfma_f32_32x32x16_bf16(a, b, c, 0, 0, 0)) {
  return __builtin_amdgcn_mfma_f32_32x32x16_bf16(a, b, c, 0, 0, 0);
}
template <typename V>
DEVINL f32x16 mfma_32x32x16_bf16(V a, V b, f32x16 c, long) {
  return __builtin_amdgcn_mfma_f32_32x32x16_bf16(
      __builtin_bit_cast(bf16x8, a), __builtin_bit_cast(bf16x8, b), c, 0, 0, 0);
}
DEVINL f32x16 mfma_bf16(short8 a, short8 b, f32x16 c) {
  return mfma_32x32x16_bf16(a, b, c, 0);
}

// ---------------- W pack kernel (unchanged, verified R2-R17) ----------------
// Packed layout per layer: [f][kb=k>>3][h][j=k&7] bf16 (granule = 1024 u16).
__global__ void pack_w_kernel(const float* __restrict__ W0,
                              const float* __restrict__ W1,
                              const float* __restrict__ W2,
                              unsigned short* __restrict__ Wt) {
  __shared__ float tile[8][132];
  const int u = blockIdx.x;
  const float* W; int FK, f, kb, base;
  if (u < 128)      { W = W0; FK = 32;  f = u >> 2;         kb = u & 3;          base = 0; }
  else if (u < 640) { W = W1; FK = 128; f = (u - 128) >> 4; kb = (u - 128) & 15; base = 131072; }
  else              { W = W2; FK = 128; f = (u - 640) >> 4; kb = (u - 640) & 15; base = 655360; }
  const int t = threadIdx.x;
#pragma unroll
  for (int i = 0; i < 4; ++i) {
    const int e = t + i * 256;  // 0..1023
    const int kk = e >> 7, h = e & 127;
    tile[kk][h] = W[(f * FK + kb * 8 + kk) * 128 + h];
  }
  __syncthreads();
  unsigned short* dst = Wt + base + f * (FK / 8) * 1024 + kb * 1024;
  const int h = t >> 1;
  const int j0 = (t & 1) * 4;
  u16x4 v;
  v.x = f2bf_rne(tile[j0 + 0][h]);
  v.y = f2bf_rne(tile[j0 + 1][h]);
  v.z = f2bf_rne(tile[j0 + 2][h]);
  v.w = f2bf_rne(tile[j0 + 3][h]);
  *(u16x4*)&dst[t * 4] = v;
}

// ---------------- layers 0/1 (R12 structure, deeper W pipeline) ------------
// Quad = 4 granule loads (16B/lane). Field f (KQ=8) = quads (2f, 2f+1).
// Per-lane granule addr: gb + q*16384 + i*4096 bytes (i = 0..3).
// Each W buffer reg is reloaded (for phase+2) right after its last MFMA use.
template <int KQ, int STEPS, int LAYER>
DEVINL void run_layer(const unsigned short* __restrict__ WtL,
                      const float* __restrict__ bias,
                      const float* x0l,  // LDS-resident x0 block [b][f][d]
                      float* __restrict__ outp, int outoff,
                      unsigned int* SB,
                      int wgb0, int mrow, int npair, int l31, int half) {
  __syncthreads();  // state in SB + x0l ready (prologue or previous epilogue)

  // B-frags (S) from SB into registers, once per layer.
  // slot (half,j) of sfr[nt][kq] holds S[r][k = kq*16 + half*8 + j],
  // r = npair*64 + nt*32 + l31. SB row k2=k/2 packs (k even lo16, k odd hi16).
  int4 sfr[2][KQ];
  const int rb = npair * 64;
#pragma unroll
  for (int nt = 0; nt < 2; ++nt) {
    const int r = rb + nt * 32 + l31;
#pragma unroll
    for (int kq = 0; kq < KQ; ++kq) {
      const int row0 = kq * 8 + half * 4;
      int4 v;
      v.x = (int)SB[(row0 + 0) * 128 + r];
      v.y = (int)SB[(row0 + 1) * 128 + r];
      v.z = (int)SB[(row0 + 2) * 128 + r];
      v.w = (int)SB[(row0 + 3) * 128 + r];
      sfr[nt][kq] = v;
    }
  }

  f32x16 zv;
#pragma unroll
  for (int e = 0; e < 16; ++e) zv[e] = 0.f;
  f32x16 outacc[2] = {zv, zv};

  const char* gb = (const char*)WtL +
                   (size_t)(half * 2048 + (mrow * 32 + l31) * 16);
  const int xb0 = (npair * 2 + 0) * 1024 + l31;  // x0l[b_local][f][d=l31]
  const int xb1 = (npair * 2 + 1) * 1024 + l31;

  auto ldg1 = [&](int q, int i) -> short8 {  // granule i of quad q
    return *(const short8*)(gb + (size_t)q * 16384 + (size_t)i * 4096);
  };
  auto ldq = [&](short8* wv, int q) {
#pragma unroll
    for (int i = 0; i < 4; ++i) wv[i] = ldg1(q, i);
  };

  if constexpr (KQ == 8) {
    // L1: field = 2 quads; 4 quad bufs; reload-after-use, distance = 1 iter
    // (2 fields = 32 MFMA/wave) instead of R12's 1 doFld.
    short8 w0[4], w1[4], w2[4], w3[4];
    ldq(w0, 0);
    ldq(w1, 1);
    ldq(w2, 2);
    ldq(w3, 3);
    __syncthreads();  // all waves hold sfr; SB free for this layer's epilogue

    auto doFldR = [&](short8* qa, short8* qb, float xs0, float xs1, int qrel) {
      f32x16 Y0, Y1;
#pragma unroll
      for (int i = 0; i < 4; ++i) {
        const short8 s0 = __builtin_bit_cast(short8, sfr[0][i]);
        const short8 s1 = __builtin_bit_cast(short8, sfr[1][i]);
        Y0 = mfma_bf16(qa[i], s0, i == 0 ? zv : Y0);
        Y1 = mfma_bf16(qa[i], s1, i == 0 ? zv : Y1);
      }
#pragma unroll
      for (int i = 0; i < 4; ++i) qa[i] = ldg1(qrel, i);  // reload for +2 flds
#pragma unroll
      for (int i = 0; i < 4; ++i) {
        const short8 s0 = __builtin_bit_cast(short8, sfr[0][4 + i]);
        const short8 s1 = __builtin_bit_cast(short8, sfr[1][4 + i]);
        Y0 = mfma_bf16(qb[i], s0, Y0);
        Y1 = mfma_bf16(qb[i], s1, Y1);
      }
#pragma unroll
      for (int i = 0; i < 4; ++i) qb[i] = ldg1(qrel + 1, i);
#pragma unroll
      for (int e = 0; e < 16; ++e) {
        outacc[0][e] += xs0 * Y0[e];
        outacc[1][e] += xs1 * Y1[e];
      }
    };

#pragma unroll 1
    for (int it = 0; it < 16; ++it) {
      const int f = 2 * it;
      const float xs00 = x0l[xb0 + f * 32], xs01 = x0l[xb1 + f * 32];
      const float xs10 = x0l[xb0 + (f + 1) * 32];
      const float xs11 = x0l[xb1 + (f + 1) * 32];
      // last iter: reload quad 0/2 (in-bounds, unused) — branch-free clamp
      const int r0 = it < 15 ? 4 * it + 4 : 0;
      const int r1 = it < 15 ? 4 * it + 6 : 2;
      doFldR(w0, w1, xs00, xs01, r0);  // field 2it   (quads 4it, 4it+1)
      doFldR(w2, w3, xs10, xs11, r1);  // field 2it+1 (quads 4it+2, 4it+3)
    }
  } else {
    // L0 (KQ=2): quad q = fields (2q, 2q+1); 2 quad bufs, reload-after-use,
    // distance = 1 iter (2 quads = 16 MFMA) instead of R12's 1 quad.
    short8 wa[4], wb[4];
    ldq(wa, 0);
    ldq(wb, 1);
    __syncthreads();

    const short8 s00 = __builtin_bit_cast(short8, sfr[0][0]);
    const short8 s01 = __builtin_bit_cast(short8, sfr[0][1]);
    const short8 s10 = __builtin_bit_cast(short8, sfr[1][0]);
    const short8 s11 = __builtin_bit_cast(short8, sfr[1][1]);

    auto doQR = [&](short8* wv, float x0a, float x1a, float x0b, float x1b,
                    int qrel) {
      f32x16 Y0 = mfma_bf16(wv[0], s00, zv);
      f32x16 Y1 = mfma_bf16(wv[0], s10, zv);
      Y0 = mfma_bf16(wv[1], s01, Y0);
      Y1 = mfma_bf16(wv[1], s11, Y1);
      wv[0] = ldg1(qrel, 0);  // reload first-field frags for quad qrel
      wv[1] = ldg1(qrel, 1);
#pragma unroll
      for (int e = 0; e < 16; ++e) {
        outacc[0][e] += x0a * Y0[e];
        outacc[1][e] += x1a * Y1[e];
      }
      f32x16 Z0 = mfma_bf16(wv[2], s00, zv);
      f32x16 Z1 = mfma_bf16(wv[2], s10, zv);
      Z0 = mfma_bf16(wv[3], s01, Z0);
      Z1 = mfma_bf16(wv[3], s11, Z1);
      wv[2] = ldg1(qrel, 2);
      wv[3] = ldg1(qrel, 3);
#pragma unroll
      for (int e = 0; e < 16; ++e) {
        outacc[0][e] += x0b * Z0[e];
        outacc[1][e] += x1b * Z1[e];
      }
    };

#pragma unroll 1
    for (int q2 = 0; q2 < 8; ++q2) {
      const int q = 2 * q2;
      const int f = 4 * q2;
      const float xA0 = x0l[xb0 + (f + 0) * 32], xA1 = x0l[xb1 + (f + 0) * 32];
      const float xB0 = x0l[xb0 + (f + 1) * 32], xB1 = x0l[xb1 + (f + 1) * 32];
      const float xC0 = x0l[xb0 + (f + 2) * 32], xC1 = x0l[xb1 + (f + 2) * 32];
      const float xD0 = x0l[xb0 + (f + 3) * 32], xD1 = x0l[xb1 + (f + 3) * 32];
      const int r0 = q2 < 7 ? q + 2 : 0;
      const int r1 = q2 < 7 ? q + 3 : 1;
      doQR(wa, xA0, xA1, xB0, xB1, r0);  // quad q   (fields f, f+1)
      doQR(wb, xC0, xC1, xD0, xD1, r1);  // quad q+1 (fields f+2, f+3)
    }
  }

  // --- epilogue (verbatim R12) ---
  // C/D layout: col = lane&31 = n; row = (reg&3)+8*(reg>>2)+4*half = h.
  float bv[16];
#pragma unroll
  for (int e = 0; e < 16; ++e)
    bv[e] = bias[mrow * 32 + (e & 3) + 8 * (e >> 2) + 4 * half];

  if constexpr (LAYER < 2) {
    // next state S'[r][h] = bf16(acc+bias), packed [h/2][r] u32 into SB
#pragma unroll
    for (int nt = 0; nt < 2; ++nt) {
      const int r = rb + nt * 32 + l31;
#pragma unroll
      for (int g = 0; g < 4; ++g) {
        const int h2 = mrow * 16 + 4 * g + 2 * half;
        const float v0 = outacc[nt][4 * g + 0] + bv[4 * g + 0];
        const float v1 = outacc[nt][4 * g + 1] + bv[4 * g + 1];
        const float v2 = outacc[nt][4 * g + 2] + bv[4 * g + 2];
        const float v3 = outacc[nt][4 * g + 3] + bv[4 * g + 3];
        SB[h2 * 128 + r] =
            (unsigned)f2bf_rne(v0) | ((unsigned)f2bf_rne(v1) << 16);
        SB[(h2 + 1) * 128 + r] =
            (unsigned)f2bf_rne(v2) | ((unsigned)f2bf_rne(v3) << 16);
      }
    }
  }

  // final output: out[b, outoff+h] = sum_d acc + 32*bias (d = l31 lanes)
#pragma unroll
  for (int nt = 0; nt < 2; ++nt) {
    float sv[16];
#pragma unroll
    for (int e = 0; e < 16; ++e) {
      float v = outacc[nt][e];
      v += __shfl_xor(v, 1);
      v += __shfl_xor(v, 2);
      v += __shfl_xor(v, 4);
      v += __shfl_xor(v, 8);
      v += __shfl_xor(v, 16);
      sv[e] = v + 32.0f * bv[e];
    }
    if (l31 == 0) {
      const int b = npair * 2 + nt;
#pragma unroll
      for (int g = 0; g < 4; ++g) {
        const int h = mrow * 32 + 8 * g + 4 * half;
        float4 o = {sv[4 * g + 0], sv[4 * g + 1], sv[4 * g + 2], sv[4 * g + 3]};
        *(float4*)&outp[b * 384 + outoff + h] = o;
      }
    }
  }
}

// ---------------- layer 2, U-trick (R12; step2 4-deep pipeline) ------------
// out2[b,h] = sum_k U[b,k]*W2[k,h] + 32*b2[h];  U[b,f*128+g] = x0_b . S2_b^T.
DEVINL void run_layer2_fast(const unsigned short* __restrict__ WtL,
                            const float* __restrict__ bias,
                            const float* x0l,
                            float* __restrict__ outp,
                            unsigned int* SB, int wgb0,
                            int w, int l31, int half, int tid) {
  __syncthreads();  // S2 in SB ready ([g/2][r=b*32+d] u32 bf16-pairs)

  f32x16 zv;
#pragma unroll
  for (int e = 0; e < 16; ++e) zv[e] = 0.f;

  // ---- step 1: U = x0_b (32f x 32d) . S2_b^T (32d x 128g), MFMA M=f,N=g,K=d
  // wave w: batch bw = w>>1, g-half gh = w&1 (2 n-tiles of g).
  const int bw = w >> 1, gh = w & 1;
  short8 a1[2];  // A[m=f=l31][k=d slots], kq=0,1  (reads from LDS x0l)
  {
    const float* xr = &x0l[bw * 1024 + l31 * 32];
#pragma unroll
    for (int kq = 0; kq < 2; ++kq) {
      const int d0 = kq * 16 + half * 8;
      union { short8 v; unsigned short u[8]; } t;
#pragma unroll
      for (int j = 0; j < 8; ++j) t.u[j] = f2bf_rne(xr[d0 + j]);
      a1[kq] = t.v;
    }
  }
  short8 bfr[2][2];  // [nt][kq]: B[k=d][n=g]: S2[b, g, d]
#pragma unroll
  for (int nt = 0; nt < 2; ++nt) {
    const int g = gh * 64 + nt * 32 + l31;
    const unsigned int* row = &SB[(g >> 1) * 128 + bw * 32];
    const int sh = (g & 1) * 16;
#pragma unroll
    for (int kq = 0; kq < 2; ++kq) {
      const int d0 = kq * 16 + half * 8;
      union { short8 v; unsigned short u[8]; } t;
#pragma unroll
      for (int j = 0; j < 8; ++j)
        t.u[j] = (unsigned short)(row[d0 + j] >> sh);
      bfr[nt][kq] = t.v;
    }
  }
  f32x16 ua[2];
#pragma unroll
  for (int nt = 0; nt < 2; ++nt) {
    ua[nt] = mfma_bf16(a1[0], bfr[nt][0], zv);
    ua[nt] = mfma_bf16(a1[1], bfr[nt][1], ua[nt]);
  }
  __syncthreads();  // all waves done reading S2 from SB

  // ---- write U into SB as U32[k2 = k/2][b] (k = f*128+g; u16 writes) ----
  unsigned short* U16 = (unsigned short*)SB;
#pragma unroll
  for (int nt = 0; nt < 2; ++nt) {
    const int g = gh * 64 + nt * 32 + l31;
#pragma unroll
    for (int reg = 0; reg < 16; ++reg) {
      const int f = (reg & 3) + 8 * (reg >> 2) + 4 * half;
      const int k = f * 128 + g;
      U16[(k >> 1) * 8 + bw * 2 + (k & 1)] = f2bf_rne(ua[nt][reg]);
    }
  }
  __syncthreads();  // U ready

  // ---- step 2: D[m=h][n=b] = sum_k W2[k,h]*U[b,k]; wave: mt=w&3, kh=w>>2 ----
  const int mt = w & 3, kh = w >> 2;
  const char* gb = (const char*)WtL +
                   (size_t)(half * 2048 + (mt * 32 + l31) * 16);
  const int bl = l31 & 3;  // lanes 4..31 duplicate b (cols unused, bounds-safe)

  auto ldq2 = [&](short8* wv, int q) {  // quad q -> kq = 4q..4q+3
#pragma unroll
    for (int i = 0; i < 4; ++i)
      wv[i] = *(const short8*)(gb + (size_t)q * 16384 + i * 4096);
  };
  auto breadq = [&](short8* bv, int q) {  // B-frags for the 4 kq of quad q
#pragma unroll
    for (int i = 0; i < 4; ++i) {
      const int row0 = (q * 4 + i) * 8 + half * 4;
      int4 v;
      v.x = (int)SB[(row0 + 0) * 4 + bl];
      v.y = (int)SB[(row0 + 1) * 4 + bl];
      v.z = (int)SB[(row0 + 2) * 4 + bl];
      v.w = (int)SB[(row0 + 3) * 4 + bl];
      bv[i] = __builtin_bit_cast(short8, v);
    }
  };

  f32x16 acc0 = zv, acc1 = zv;
  short8 qa[4], qb[4], qc[4], qd[4], Ba[4], Bb[4], Bc[4], Bd[4];
  const int q0 = kh * 32;  // 32 quads = 128 kq per wave
  ldq2(qa, q0 + 0); breadq(Ba, q0 + 0);
  ldq2(qb, q0 + 1); breadq(Bb, q0 + 1);
  ldq2(qc, q0 + 2); breadq(Bc, q0 + 2);
  ldq2(qd, q0 + 3); breadq(Bd, q0 + 3);
#pragma unroll 1
  for (int qq = 0; qq < 8; ++qq) {  // 4 quads per iteration
    const int q = q0 + 4 * qq;
    const bool more = qq < 7;
#pragma unroll
    for (int i = 0; i < 4; ++i) acc0 = mfma_bf16(qa[i], Ba[i], acc0);
    { const int r = more ? q + 4 : q0; ldq2(qa, r); breadq(Ba, r); }
#pragma unroll
    for (int i = 0; i < 4; ++i) acc1 = mfma_bf16(qb[i], Bb[i], acc1);
    { const int r = more ? q + 5 : q0; ldq2(qb, r); breadq(Bb, r); }
#pragma unroll
    for (int i = 0; i < 4; ++i) acc0 = mfma_bf16(qc[i], Bc[i], acc0);
    { const int r = more ? q + 6 : q0; ldq2(qc, r); breadq(Bc, r); }
#pragma unroll
    for (int i = 0; i < 4; ++i) acc1 = mfma_bf16(qd[i], Bd[i], acc1);
    { const int r = more ? q + 7 : q0; ldq2(qd, r); breadq(Bd, r); }
  }
#pragma unroll
  for (int e = 0; e < 16; ++e) acc0[e] += acc1[e];

  __syncthreads();  // all waves done reading U from SB

  // ---- partials P[o = b*128 + h][kh] f32 into SB (4KB), then reduce ----
  float* P = (float*)SB;
  if (l31 < 4) {
#pragma unroll
    for (int reg = 0; reg < 16; ++reg) {
      const int h = mt * 32 + (reg & 3) + 8 * (reg >> 2) + 4 * half;
      P[(l31 * 128 + h) * 2 + kh] = acc0[reg];
    }
  }
  __syncthreads();
  {
    const int b = tid >> 7, h = tid & 127;  // tid 0..511 -> all outputs
    const float v = P[tid * 2] + P[tid * 2 + 1] + 32.0f * bias[h];
    outp[b * 384 + 256 + h] = v;
  }
}

__global__ __launch_bounds__(512, 1) void cin_kernel(
    const float* __restrict__ x0g, const unsigned short* __restrict__ Wt,
    const float* __restrict__ b0, const float* __restrict__ b1,
    const float* __restrict__ b2, float* __restrict__ out) {
  __shared__ unsigned int SB[64 * 128];  // 32KB state / U / partials
  __shared__ __align__(16) float x0l[4096];  // 16KB x0 block [b][f][d]

  const int t = threadIdx.x;
  const int lane = t & 63;
  const int w = t >> 6;      // 0..7
  const int mrow = w & 3;    // h-tile of 32 (L0/L1)
  const int npair = w >> 2;  // batch pair (L0/L1)
  const int l31 = lane & 31, half = lane >> 5;
  const int wgb0 = blockIdx.x * 4;  // 4 batches per WG

  // prologue A: stage x0 block -> LDS via global_load_lds (16 chunks x 1KB)
  const float* xsrc = x0g + (size_t)wgb0 * 1024;
#pragma unroll
  for (int c = 0; c < 2; ++c) {
    const int chunk = w * 2 + c;
    gload_lds16(xsrc + chunk * 256 + lane * 4, x0l + chunk * 256);
  }
  // prologue B: S1 = bf16(x0^T) -> SB ([g/2][r] u32, r = b_local*32+d)
#pragma unroll
  for (int s = 0; s < 4; ++s) {
    const int i = t + s * 512;  // 0..2047
    const int r = i & 127, g2 = i >> 7;
    const float* p = &x0g[(wgb0 + (r >> 5)) * 1024 + (2 * g2) * 32 + (r & 31)];
    SB[g2 * 128 + r] =
        (unsigned)f2bf_rne(p[0]) | ((unsigned)f2bf_rne(p[32]) << 16);
  }
  // visibility handled by the entry barrier in run_layer (full drain)

  float* outp = out + (size_t)wgb0 * 384;
  run_layer<2, 8, 0>(Wt, b0, x0l, outp, 0, SB, wgb0, mrow, npair, l31, half);
  run_layer<8, 32, 1>(Wt + 131072, b1, x0l, outp, 128, SB,
                      wgb0, mrow, npair, l31, half);
  run_layer2_fast(Wt + 655360, b2, x0l, outp, SB, wgb0, w, l31, half, t);
}

extern "C" void kernel_launch(void* const* d_in, const int* in_sizes, int n_in,
                              void* d_out, int out_size, void* d_ws, size_t ws_size,
                              hipStream_t stream) {
  (void)in_sizes; (void)n_in; (void)out_size; (void)ws_size;
  const float* x0 = (const float*)d_in[0];
  const float* W0 = (const float*)d_in[1];
  const float* W1 = (const float*)d_in[2];
  const float* W2 = (const float*)d_in[3];
  const float* b0 = (const float*)d_in[4];
  const float* b1 = (const float*)d_in[5];
  const float* b2 = (const float*)d_in[6];
  unsigned short* Wt = (unsigned short*)d_ws;  // 2,359,296 B

  pack_w_kernel<<<1152, 256, 0, stream>>>(W0, W1, W2, Wt);
  // 256 WGs x 512 thr = 1 WG/CU (8 waves, 2/SIMD)
  cin_kernel<<<256, 512, 0, stream>>>(x0, Wt, b0, b1, b2, (float*)d_out);
}